// Round 7
// baseline (151.004 us; speedup 1.0000x reference)
//
#include <hip/hip_runtime.h>
#include <hip/hip_bf16.h>
#include <math.h>

#define Bn 4
#define Nn 512
#define Dn 128
#define Hn 64
#define TT 2048
#define EPB 8                    // table entries per k0 block
#define K0B ((TT + 1 + EPB - 1) / EPB)   // 257 blocks

__device__ __forceinline__ float silu_f(float x) {
    return x * (1.0f / (1.0f + __expf(-x)));
}

// ---------------------------------------------------------------------------
// k0 v2: tabulate radial MLP G(x): scalar -> R^128 at x = e/TT, e = 0..TT.
// 257 blocks x 256 threads; all weights staged in LDS once per block; each
// block computes 8 entries (4 concurrent across waves x 2 rounds).  Replaces
// the R4-R6 one-wave-per-entry version that was latency-serial on global
// weight loads (~48 us for 50 MFLOP).
// ---------------------------------------------------------------------------
struct K0S {
    float rW2s[Hn][Hn];      // [kk][k] : lane k reads stride-1 (2-way, free)
    float rW3s[Hn][Dn];      // [kk][d]
    float rW1s[Hn], rb1s[Hn], rg1s[Hn], rb2s[Hn], rg2s[Hn];
    float rb3s[Dn];
    float h1buf[4][Hn];      // per-wave normalized h1
    float h2buf[4][Hn];      // per-wave normalized h2
};

__global__ __launch_bounds__(256)
void k0_build_table(const float* __restrict__ rW1, const float* __restrict__ rb1,
                    const float* __restrict__ rg1,
                    const float* __restrict__ rW2, const float* __restrict__ rb2,
                    const float* __restrict__ rg2,
                    const float* __restrict__ rW3, const float* __restrict__ rb3,
                    __hip_bfloat16* __restrict__ table)
{
    __shared__ K0S sm;
    const int t    = threadIdx.x;
    const int k    = t & 63;
    const int wv   = t >> 6;
    const int blk  = blockIdx.x;

    // ---- stage all weights in LDS (coalesced) ----
    #pragma unroll
    for (int idx = t; idx < Hn * Hn; idx += 256)
        sm.rW2s[idx >> 6][idx & 63] = rW2[idx];
    #pragma unroll
    for (int idx = t; idx < Hn * Dn; idx += 256)
        sm.rW3s[idx >> 7][idx & 127] = rW3[idx];
    if (t < Hn) {
        sm.rW1s[t] = rW1[t];
        sm.rb1s[t] = rb1[t];
        sm.rg1s[t] = rg1[t];
        sm.rb2s[t] = rb2[t];
        sm.rg2s[t] = rg2[t];
    }
    if (t < Dn) sm.rb3s[t] = rb3[t];
    __syncthreads();

    for (int r = 0; r < 2; ++r) {
        const int e = blk * EPB + r * 4 + wv;      // may exceed TT; store guarded
        const float x = (float)e * (1.0f / (float)TT);

        // layer 1: silu(x*rW1+rb1), LN(rg1)
        float h = silu_f(x * sm.rW1s[k] + sm.rb1s[k]);
        float s1 = h, s2 = h * h;
        #pragma unroll
        for (int m = 1; m < 64; m <<= 1) { s1 += __shfl_xor(s1, m); s2 += __shfl_xor(s2, m); }
        float mean = s1 * (1.0f / 64.0f);
        float var  = s2 * (1.0f / 64.0f) - mean * mean;
        float rs   = rsqrtf(var + 1e-5f);
        sm.h1buf[wv][k] = (h - mean) * rs * sm.rg1s[k];
        __syncthreads();

        // layer 2: silu(h1n @ rW2 + rb2), LN(rg2)
        float p = 0.f;
        #pragma unroll 8
        for (int kk = 0; kk < Hn; ++kk) p += sm.h1buf[wv][kk] * sm.rW2s[kk][k];
        float h2 = silu_f(p + sm.rb2s[k]);
        s1 = h2; s2 = h2 * h2;
        #pragma unroll
        for (int m = 1; m < 64; m <<= 1) { s1 += __shfl_xor(s1, m); s2 += __shfl_xor(s2, m); }
        mean = s1 * (1.0f / 64.0f);
        var  = s2 * (1.0f / 64.0f) - mean * mean;
        rs   = rsqrtf(var + 1e-5f);
        sm.h2buf[wv][k] = (h2 - mean) * rs * sm.rg2s[k];
        __syncthreads();

        // layer 3: h2n @ rW3 + rb3 -> bf16 table row
        #pragma unroll
        for (int dd = 0; dd < 2; ++dd) {
            const int d = dd * 64 + k;
            float f = sm.rb3s[d];
            #pragma unroll 8
            for (int kk = 0; kk < Hn; ++kk) f += sm.h2buf[wv][kk] * sm.rW3s[kk][d];
            if (e <= TT) table[e * Dn + d] = __float2bfloat16(f);
        }
        __syncthreads();   // protect h1buf/h2buf for next round
    }
}

// ---------------------------------------------------------------------------
// k1: fused contraction + node MLP.  Block per (b,i), 256 threads.
//   Stage: ballot-based deterministic compaction of active j (w != 0) into
//   LDS entry lists (no atomics; order = lane order, replay-stable).
//   Main loop: branch-free, uniform trip count (padded to x16), waves stride
//   entries 4-way, lane owns d0 = 2*lane; loads pipeline freely.
//   Epilogue: R4/R6-verified node MLP.
// ---------------------------------------------------------------------------
struct K1S {
    float2 wfE[528];         // (w, frac) per active entry (+pad)
    int    metaE[528];       // i0 | atom<<16
    int    wcnt[4];
    float  accs[4][64][2];
    float  xs[256];
    float  r1[2], r2[2];
    float  x2[128];
};

__global__ __launch_bounds__(256)
void k1_fused(const int* __restrict__ atoms, const float* __restrict__ rel,
              const int* __restrict__ adj, const int* __restrict__ mask,
              const float* __restrict__ soft, const float* __restrict__ ntab,
              const __hip_bfloat16* __restrict__ table,
              const float* __restrict__ atom_tab,
              const float* __restrict__ nW1, const float* __restrict__ nb1,
              const float* __restrict__ ng,
              const float* __restrict__ nW2, const float* __restrict__ nb2,
              float* __restrict__ out)
{
    __shared__ K1S sm;
    const int t    = threadIdx.x;
    const int lane = t & 63;
    const int wv   = t >> 6;
    const int bi   = blockIdx.x;        // b*N + i
    const int b    = bi >> 9;
    const int i    = bi & 511;
    const int rowbase = bi * Nn;

    // ---- stage + deterministic compaction (2 rounds of 256 j) ----
    int total = 0;
    for (int it = 0; it < 2; ++it) {
        const int j = it * 256 + t;
        const float dist = rel[rowbase + j];
        const int   adjv = adj[rowbase + j];
        const int   mk   = mask[b * Nn + j];
        const float w = (adjv != 0 && mk != 0 && j != i) ? soft[rowbase + j] : 0.0f;
        float xx = dist * (float)TT;
        int   xi = (int)xx;
        xi = min(max(xi, 0), TT - 1);

        const bool act = (w != 0.0f);
        const unsigned long long bm = __ballot(act);
        const int before = __popcll(bm & ((1ull << lane) - 1ull));
        if (lane == 0) sm.wcnt[wv] = (int)__popcll(bm);
        __syncthreads();
        int base = total;
        for (int q = 0; q < 4; ++q) {
            if (q < wv) base += sm.wcnt[q];
            total += sm.wcnt[q];
        }
        if (act) {
            const int pos = base + before;
            sm.wfE[pos]   = make_float2(w, xx - (float)xi);
            sm.metaE[pos] = xi | (atoms[b * Nn + j] << 16);
        }
        __syncthreads();   // wcnt reused next round
    }

    // pad entry list to multiple of 16 (uniform wave trip count)
    const int cnt  = total;                  // <= 511 (j==i always inactive)
    const int cntP = (cnt + 15) & ~15;
    if (t < cntP - cnt) {
        sm.wfE[cnt + t]   = make_float2(0.0f, 0.0f);
        sm.metaE[cnt + t] = 0;
    }
    __syncthreads();

    // ---- branch-free compacted contraction ----
    const int d0 = lane * 2;
    float a0 = 0.f, a1 = 0.f;
    const int trips = cntP >> 2;             // entries per wave (mult of 4)
    #pragma unroll 4
    for (int n = 0; n < trips; ++n) {
        const int e = wv + (n << 2);
        const float2 wf  = sm.wfE[e];        // broadcast b64
        const int   meta = sm.metaE[e];
        const int   i0   = meta & 0xFFFF;
        const int   at   = meta >> 16;
        const __hip_bfloat162 t0 = *(const __hip_bfloat162*)&table[i0 * Dn + d0];
        const __hip_bfloat162 t1 = *(const __hip_bfloat162*)&table[(i0 + 1) * Dn + d0];
        const float2 nv = *(const float2*)&ntab[at * Dn + d0];
        const float v00 = __bfloat162float(t0.x), v01 = __bfloat162float(t0.y);
        const float v10 = __bfloat162float(t1.x), v11 = __bfloat162float(t1.y);
        const float val0 = v00 + wf.y * (v10 - v00);
        const float val1 = v01 + wf.y * (v11 - v01);
        a0 += (wf.x * nv.x) * val0;
        a1 += (wf.x * nv.y) * val1;
    }
    sm.accs[wv][lane][0] = a0;
    sm.accs[wv][lane][1] = a1;
    __syncthreads();

    // ---- fused node-MLP epilogue (R4/R6-verified logic) ----
    const int a = atoms[bi];
    if (t < Dn) {
        float r = 0.f;
        #pragma unroll
        for (int q = 0; q < 4; ++q) r += sm.accs[q][t >> 1][t & 1];
        sm.xs[t]       = atom_tab[a * Dn + t];
        sm.xs[128 + t] = r;
    }
    __syncthreads();

    float s = 0.f;
    if (t < Dn) {
        float p0 = 0.f, p1 = 0.f, p2 = 0.f, p3 = 0.f;
        #pragma unroll 4
        for (int c = 0; c < 256; c += 4) {
            p0 += sm.xs[c + 0] * nW1[(c + 0) * Dn + t];
            p1 += sm.xs[c + 1] * nW1[(c + 1) * Dn + t];
            p2 += sm.xs[c + 2] * nW1[(c + 2) * Dn + t];
            p3 += sm.xs[c + 3] * nW1[(c + 3) * Dn + t];
        }
        s = (p0 + p1) + (p2 + p3) + nb1[t];
        float a1r = s, a2r = s * s;
        #pragma unroll
        for (int off = 32; off > 0; off >>= 1) {
            a1r += __shfl_down(a1r, off);
            a2r += __shfl_down(a2r, off);
        }
        if ((t & 63) == 0) { sm.r1[t >> 6] = a1r; sm.r2[t >> 6] = a2r; }
    }
    __syncthreads();

    if (t < Dn) {
        const float S1 = sm.r1[0] + sm.r1[1];
        const float S2 = sm.r2[0] + sm.r2[1];
        const float m  = S1 * (1.0f / 128.0f);
        const float vr = S2 * (1.0f / 128.0f) - m * m;
        const float rs = rsqrtf(vr + 1e-5f);
        sm.x2[t] = silu_f((s - m) * rs * ng[t]);   // LN first, THEN silu
    }
    __syncthreads();

    if (t < Dn) {
        float q0 = 0.f, q1 = 0.f, q2 = 0.f, q3 = 0.f;
        #pragma unroll 4
        for (int c = 0; c < 128; c += 4) {
            q0 += sm.x2[c + 0] * nW2[(c + 0) * Dn + t];
            q1 += sm.x2[c + 1] * nW2[(c + 1) * Dn + t];
            q2 += sm.x2[c + 2] * nW2[(c + 2) * Dn + t];
            q3 += sm.x2[c + 3] * nW2[(c + 3) * Dn + t];
        }
        out[bi * Dn + t] = (q0 + q1) + (q2 + q3) + nb2[t];
    }
}

// ---------------------------------------------------------------------------
extern "C" void kernel_launch(void* const* d_in, const int* in_sizes, int n_in,
                              void* d_out, int out_size, void* d_ws, size_t ws_size,
                              hipStream_t stream)
{
    (void)in_sizes; (void)n_in; (void)out_size; (void)ws_size;

    const int*   atoms = (const int*)d_in[0];
    const float* rel   = (const float*)d_in[1];
    const int*   adj   = (const int*)d_in[2];
    const int*   mask  = (const int*)d_in[3];
    const float* soft  = (const float*)d_in[4];
    const float* atab  = (const float*)d_in[5];
    const float* ntab  = (const float*)d_in[6];
    const float* rW1   = (const float*)d_in[7];
    const float* rb1   = (const float*)d_in[8];
    const float* rg1   = (const float*)d_in[9];
    const float* rW2   = (const float*)d_in[10];
    const float* rb2   = (const float*)d_in[11];
    const float* rg2   = (const float*)d_in[12];
    const float* rW3   = (const float*)d_in[13];
    const float* rb3   = (const float*)d_in[14];
    const float* nW1   = (const float*)d_in[15];
    const float* nb1   = (const float*)d_in[16];
    const float* ng    = (const float*)d_in[17];
    const float* nW2   = (const float*)d_in[18];
    const float* nb2   = (const float*)d_in[19];

    __hip_bfloat16* table = (__hip_bfloat16*)d_ws;   // (TT+1) x 128 bf16
    float* out = (float*)d_out;

    hipLaunchKernelGGL(k0_build_table, dim3(K0B), dim3(256), 0, stream,
                       rW1, rb1, rg1, rW2, rb2, rg2, rW3, rb3, table);
    hipLaunchKernelGGL(k1_fused, dim3(Bn * Nn), dim3(256), 0, stream,
                       atoms, rel, adj, mask, soft, ntab, table,
                       atab, nW1, nb1, ng, nW2, nb2, out);
}